// Round 6
// baseline (1064.870 us; speedup 1.0000x reference)
//
#include <hip/hip_runtime.h>
#include <math.h>

// SigmoidRouter: x(16384,4096) f32, gate_w(64,4096) f32, bias(64) f32
// out (float*): weights[tokens*8] ++ indices-as-float[tokens*8] ++ loss[1]
//
// Strategy: f32 main pass (no LDS in the K loop; x via wave-uniform scalar
// loads, gw transposed+coalesced through L1). Top-9 selection on f32 logits;
// tokens whose rank-adjacent logit gaps < TAU are recomputed exactly in f64
// by a repair kernel (R4-proven math). TAU = 1e-4 ~ 250 sigma of f32 error.

constexpr int DIM     = 4096;
constexpr int NE      = 64;
constexpr int TOPK    = 8;
constexpr float EPS   = 1e-6f;
constexpr float TAU   = 1e-4f;
constexpr int T       = 8;          // tokens per wave
constexpr int WPB     = 4;          // waves per block
constexpr int TPB_TOK = T * WPB;    // 32 tokens per block
constexpr int MAXFLAG = 16384;
constexpr int REPAIR_WAVES = 2048;  // 512 blocks x 4 waves

__device__ inline double shfl_xor_d(double v, int off) {
    long long xx = __double_as_longlong(v);
    int lo = (int)(unsigned int)(xx & 0xffffffffLL);
    int hi = (int)(xx >> 32);
    lo = __shfl_xor(lo, off);
    hi = __shfl_xor(hi, off);
    long long y = ((long long)hi << 32) | (unsigned int)lo;
    return __longlong_as_double(y);
}

// gw[e][k] -> gwT4[k4][e] (float4 of 4 consecutive k), and gwd2[k2][e] (f64 pairs)
__global__ __launch_bounds__(256)
void prep(const float* __restrict__ gw, float4* __restrict__ gwT4,
          double2* __restrict__ gwd2, int* __restrict__ flag_cnt)
{
    int g  = blockIdx.x * 256 + threadIdx.x;   // 65536 threads
    int e  = g >> 10;                          // DIM/4 = 1024 k4 per expert
    int k4 = g & 1023;
    float4 v = *reinterpret_cast<const float4*>(&gw[(size_t)e * DIM + 4 * k4]);
    gwT4[(size_t)k4 * NE + e] = v;
    double2 d0; d0.x = (double)v.x; d0.y = (double)v.y;
    double2 d1; d1.x = (double)v.z; d1.y = (double)v.w;
    gwd2[(size_t)(2 * k4)     * NE + e] = d0;
    gwd2[(size_t)(2 * k4 + 1) * NE + e] = d1;
    if (g == 0) *flag_cnt = 0;
}

__global__ __launch_bounds__(256)
void router_main(const float* __restrict__ x, const float4* __restrict__ gwT4,
                 const float* __restrict__ bias, float* __restrict__ out,
                 float* __restrict__ ws_ssum, float* __restrict__ ws_cnt,
                 int* __restrict__ flag_cnt, int* __restrict__ flag_list,
                 int tokens)
{
    __shared__ float red_s[WPB][NE];
    __shared__ float red_c[WPB][NE];

    const int tid  = threadIdx.x;
    const int wave = tid >> 6;
    const int lane = tid & 63;
    const int wtok = __builtin_amdgcn_readfirstlane(blockIdx.x * TPB_TOK + wave * T);
    const float* xb = x + (size_t)wtok * DIM;   // wave-uniform base -> scalar loads
    const float4* gp = gwT4 + lane;

    float acc[T];
    #pragma unroll
    for (int t = 0; t < T; ++t) acc[t] = 0.f;

    #pragma unroll 2
    for (int k4 = 0; k4 < DIM / 4; ++k4) {
        float4 gv = gp[(size_t)k4 * NE];        // coalesced, L1-hot
        #pragma unroll
        for (int t = 0; t < T; ++t) {
            float4 xv = *reinterpret_cast<const float4*>(xb + (size_t)t * DIM + 4 * k4);
            acc[t] = fmaf(gv.x, xv.x, acc[t]);
            acc[t] = fmaf(gv.y, xv.y, acc[t]);
            acc[t] = fmaf(gv.z, xv.z, acc[t]);
            acc[t] = fmaf(gv.w, xv.w, acc[t]);
        }
    }

    const float b = bias[lane];
    float my_ssum = 0.f, my_cnt = 0.f;

    #pragma unroll 1
    for (int t = 0; t < T; ++t) {
        float logit = acc[t] + b;
        float sig = 1.f / (1.f + expf(-logit));
        float S = sig;
        #pragma unroll
        for (int off = 32; off; off >>= 1) S += __shfl_xor(S, off);
        float ns = sig / (S + EPS);
        my_ssum += ns;

        float key = logit;                      // select on logits (monotone)
        float topsum = 0.f, myval = 0.f;
        int   myidx = 0;
        float prevv = 0.f, mingap = 1e30f;
        #pragma unroll
        for (int k = 0; k < TOPK + 1; ++k) {    // 9 rounds: 8 picks + rank-9 gap
            float v = key; int id = lane;
            #pragma unroll
            for (int off = 32; off; off >>= 1) {
                float ov = __shfl_xor(v, off);
                int   oi = __shfl_xor(id, off);
                if (ov > v || (ov == v && oi < id)) { v = ov; id = oi; }
            }
            if (k > 0) mingap = fminf(mingap, prevv - v);
            prevv = v;
            if (k < TOPK) {
                float nsw = __shfl(ns, id);
                topsum += nsw;
                if (lane == k)  { myval = nsw; myidx = id; }
                if (lane == id) { key = -1e30f; my_cnt += 1.f; }
            }
        }
        int tok = wtok + t;
        float wnorm = myval / (topsum + EPS);
        if (lane < TOPK) {
            out[(size_t)tok * TOPK + lane] = wnorm;
            out[(size_t)tokens * TOPK + (size_t)tok * TOPK + lane] = (float)myidx;
        }
        if (lane == 0 && mingap < TAU) {
            int p = atomicAdd(flag_cnt, 1);
            if (p < MAXFLAG) flag_list[p] = tok;
        }
    }

    red_s[wave][lane] = my_ssum;
    red_c[wave][lane] = my_cnt;
    __syncthreads();
    if (tid < NE) {
        float s = red_s[0][tid] + red_s[1][tid] + red_s[2][tid] + red_s[3][tid];
        float c = red_c[0][tid] + red_c[1][tid] + red_c[2][tid] + red_c[3][tid];
        ws_ssum[(size_t)blockIdx.x * NE + tid] = s;
        ws_cnt [(size_t)blockIdx.x * NE + tid] = c;
    }
}

// Exact f64 recompute of flagged tokens (same math as the R4-passing kernel).
__global__ __launch_bounds__(256)
void router_repair(const float* __restrict__ x, const double2* __restrict__ gwd2,
                   const float* __restrict__ bias, float* __restrict__ out,
                   const int* __restrict__ flag_cnt, const int* __restrict__ flag_list,
                   int tokens)
{
    const int lane = threadIdx.x & 63;
    const int wid  = __builtin_amdgcn_readfirstlane(
                        (int)((blockIdx.x * 256 + threadIdx.x) >> 6));
    int n = *flag_cnt;
    if (n > MAXFLAG) n = MAXFLAG;

    for (int i = wid; i < n; i += REPAIR_WAVES) {
        const int tok = __builtin_amdgcn_readfirstlane(flag_list[i]);
        const float* xr = x + (size_t)tok * DIM;
        const double2* gb = gwd2 + lane;
        double acc = 0.0;
        for (int k2 = 0; k2 < DIM / 2; ++k2) {
            double2 g = gb[(size_t)k2 * NE];
            float x0 = xr[2 * k2];
            float x1 = xr[2 * k2 + 1];
            acc = fma((double)x0, g.x, acc);
            acc = fma((double)x1, g.y, acc);
        }
        double dl = acc + (double)bias[lane];

        float sig = 1.f / (1.f + expf(-(float)dl));
        float S = sig;
        #pragma unroll
        for (int off = 32; off; off >>= 1) S += __shfl_xor(S, off);
        float ns = sig / (S + EPS);

        double key = dl;
        float topsum = 0.f, myval = 0.f;
        int   myidx = 0;
        #pragma unroll
        for (int k = 0; k < TOPK; ++k) {
            double kv = key; int id = lane;
            #pragma unroll
            for (int off = 32; off; off >>= 1) {
                double okv = shfl_xor_d(kv, off);
                int    oi  = __shfl_xor(id, off);
                if (okv > kv || (okv == kv && oi < id)) { kv = okv; id = oi; }
            }
            float nsw = __shfl(ns, id);
            topsum += nsw;
            if (lane == k)  { myval = nsw; myidx = id; }
            if (lane == id) key = -1.0e300;
        }
        if (lane < TOPK) {
            out[(size_t)tok * TOPK + lane] = myval / (topsum + EPS);
            out[(size_t)tokens * TOPK + (size_t)tok * TOPK + lane] = (float)myidx;
        }
    }
}

__global__ __launch_bounds__(256)
void router_loss(const float* __restrict__ ws_ssum, const float* __restrict__ ws_cnt,
                 float* __restrict__ out, int nblocks, int tokens)
{
    __shared__ float ps[4][NE];
    __shared__ float pc[4][NE];
    const int e  = threadIdx.x & 63;
    const int sl = threadIdx.x >> 6;
    float s = 0.f, c = 0.f;
    for (int bb = sl; bb < nblocks; bb += 4) {
        s += ws_ssum[(size_t)bb * NE + e];
        c += ws_cnt [(size_t)bb * NE + e];
    }
    ps[sl][e] = s; pc[sl][e] = c;
    __syncthreads();
    if (threadIdx.x < NE) {
        float st = ps[0][e] + ps[1][e] + ps[2][e] + ps[3][e];
        float ct = pc[0][e] + pc[1][e] + pc[2][e] + pc[3][e];
        float prod = st * ct;
        #pragma unroll
        for (int off = 32; off; off >>= 1) prod += __shfl_xor(prod, off);
        if (threadIdx.x == 0) {
            float Tn = (float)tokens;
            out[(size_t)tokens * TOPK * 2] = (float)NE * prod / (Tn * Tn);
        }
    }
}

extern "C" void kernel_launch(void* const* d_in, const int* in_sizes, int n_in,
                              void* d_out, int out_size, void* d_ws, size_t ws_size,
                              hipStream_t stream)
{
    const float* x    = (const float*)d_in[0];
    const float* gw   = (const float*)d_in[1];
    const float* bias = (const float*)d_in[2];
    float* out = (float*)d_out;

    const int tokens  = in_sizes[0] / DIM;          // 16384
    const int nblocks = tokens / TPB_TOK;           // 512

    char* wsb = (char*)d_ws;
    float4*  gwT4     = (float4*) (wsb);                         // 1 MB
    double2* gwd2     = (double2*)(wsb + (1u << 20));            // 2 MB
    int*     flag_cnt = (int*)    (wsb + (3u << 20));
    int*     flag_list= (int*)    (wsb + (3u << 20) + 64);
    float*   ws_ssum  = (float*)  (wsb + (3u << 20) + 64 + MAXFLAG * sizeof(int));
    float*   ws_cnt   = ws_ssum + (size_t)nblocks * NE;

    prep<<<NE * (DIM / 4) / 256, 256, 0, stream>>>(gw, gwT4, gwd2, flag_cnt);
    router_main<<<nblocks, 256, 0, stream>>>(x, gwT4, bias, out, ws_ssum, ws_cnt,
                                             flag_cnt, flag_list, tokens);
    router_repair<<<REPAIR_WAVES / 4, 256, 0, stream>>>(x, gwd2, bias, out,
                                                        flag_cnt, flag_list, tokens);
    router_loss<<<1, 256, 0, stream>>>(ws_ssum, ws_cnt, out, nblocks, tokens);
}